// Round 1
// baseline (183.378 us; speedup 1.0000x reference)
//
#include <hip/hip_runtime.h>
#include <hip/hip_bf16.h>
#include <stdint.h>

#define B_    8
#define CIN   64
#define COUT  64
#define NPATH 9
#define H_    128
#define W_    128
#define HW    16384
#define PTOT  131072   // B*H*W

typedef float  f32x4  __attribute__((ext_vector_type(4)));
typedef __bf16 bf16x8 __attribute__((ext_vector_type(8)));
typedef short  short8 __attribute__((ext_vector_type(8)));

__device__ __forceinline__ unsigned short f2bf(float f) {
    __bf16 b = (__bf16)f;
    return __builtin_bit_cast(unsigned short, b);
}

// ---------------------------------------------------------------- K0a:
// x (B,CIN,H,W) f32  ->  Xb (B,H,W,CIN) bf16   (LDS tile transpose)
__global__ void k_x_to_bf16_nhwc(const float* __restrict__ x,
                                 unsigned short* __restrict__ Xb) {
    __shared__ float tile[64][65];
    int b = blockIdx.z, h = blockIdx.y, w0 = blockIdx.x * 64;
    int t = threadIdx.x;
    #pragma unroll
    for (int i = 0; i < 16; ++i) {
        int f = i * 256 + t;
        int ci = f >> 6, w = f & 63;
        tile[ci][w] = x[((b * 64 + ci) * 128 + h) * 128 + w0 + w];
    }
    __syncthreads();
    #pragma unroll
    for (int i = 0; i < 16; ++i) {
        int f = i * 256 + t;
        int w = f >> 6, ci = f & 63;
        Xb[(((b * 128 + h) * 128) + w0 + w) * 64 + ci] = f2bf(tile[ci][w]);
    }
}

// ---------------------------------------------------------------- K0b:
// kernels_w (N,COUT,CIN,3,3) f32 -> Wb[n][c][tap][ci] bf16
__global__ void k_w_to_bf16(const float* __restrict__ kw,
                            unsigned short* __restrict__ Wb) {
    int o = blockIdx.x * 256 + threadIdx.x;     // 331776 total
    int ci  = o & 63;
    int r   = o >> 6;
    int tap = r % 9;
    int c   = (r / 9) & 63;
    int n   = r / 576;
    Wb[o] = f2bf(kw[(((n * 64 + c) * 64) + ci) * 9 + tap]);
}

// ---------------------------------------------------------------- K1:
// fp32 observer scores + argmax + ordered compaction into per-path lists
__global__ void k_scores_bin(const float* __restrict__ x,
                             const float* __restrict__ w1, const float* __restrict__ b1,
                             const float* __restrict__ w2, const float* __restrict__ b2,
                             unsigned* __restrict__ gcnt, unsigned* __restrict__ lists) {
    __shared__ float sw1[2048];   // [32][64]
    __shared__ float sw2[288];    // [9][32]
    __shared__ float sb1[32];
    __shared__ float sb2[9];
    __shared__ unsigned scnt[9];
    __shared__ unsigned sbase[9];
    int t = threadIdx.x;
    #pragma unroll
    for (int i = 0; i < 8; ++i) sw1[t + i * 256] = w1[t + i * 256];
    for (int i = t; i < 288; i += 256) sw2[i] = w2[i];
    if (t < 32) sb1[t] = b1[t];
    if (t < 9)  { sb2[t] = b2[t]; scnt[t] = 0u; }
    __syncthreads();

    int p  = blockIdx.x * 256 + t;
    int b  = p >> 14, hw = p & 16383;
    const float* xp = x + (size_t)b * 64 * HW + hw;
    float xv[64];
    #pragma unroll
    for (int ci = 0; ci < 64; ++ci) xv[ci] = xp[ci * HW];

    float s[9];
    #pragma unroll
    for (int nn = 0; nn < 9; ++nn) s[nn] = sb2[nn];

    for (int j = 0; j < 32; ++j) {
        float a = sb1[j];
        const float4* wv = (const float4*)&sw1[j * 64];
        #pragma unroll
        for (int q = 0; q < 16; ++q) {
            float4 v = wv[q];
            a += xv[q*4+0]*v.x + xv[q*4+1]*v.y + xv[q*4+2]*v.z + xv[q*4+3]*v.w;
        }
        float hsig = tanhf(a);
        #pragma unroll
        for (int nn = 0; nn < 9; ++nn) s[nn] += hsig * sw2[nn * 32 + j];
    }
    float best = s[0]; int bi = 0;
    #pragma unroll
    for (int nn = 1; nn < 9; ++nn) if (s[nn] > best) { best = s[nn]; bi = nn; }

    unsigned rank = atomicAdd(&scnt[bi], 1u);
    __syncthreads();
    if (t < 9) sbase[t] = atomicAdd(&gcnt[t], scnt[t]);
    __syncthreads();
    lists[bi * PTOT + sbase[bi] + rank] = (unsigned)p;
}

// ---------------------------------------------------------------- K2:
// gathered implicit-GEMM selected conv (bf16 MFMA) + bias + relu, scatter to out
__global__ __launch_bounds__(256) void k_conv_sel(
        const unsigned short* __restrict__ Xb, const unsigned short* __restrict__ Wb,
        const float* __restrict__ kb, const unsigned* __restrict__ gcnt,
        const unsigned* __restrict__ lists, float* __restrict__ out) {
    int n = blockIdx.y;
    unsigned cnt  = gcnt[n];
    unsigned base = blockIdx.x * 64u;
    if (base >= cnt) return;
    int npix = (int)min(64u, cnt - base);
    int t = threadIdx.x;
    int wid = t >> 6, lane = t & 63;
    int l15 = lane & 15, kg = lane >> 4;
    const unsigned* lst = lists + n * PTOT + base;

    int xb[4], ob[4], hh[4], wwv[4], val[4];
    #pragma unroll
    for (int f = 0; f < 4; ++f) {
        int px = f * 16 + l15;
        int pc = px < npix ? px : npix - 1;
        unsigned p = lst[pc];
        int b = p >> 14, hw = p & 16383;
        int h = hw >> 7, w = hw & 127;
        xb[f]  = (((b * 128 + h) * 128) + w) * 64;
        ob[f]  = b * 64 * HW + hw;
        hh[f]  = h; wwv[f] = w;
        val[f] = px < npix;
    }
    const unsigned short* WbA = Wb + n * 36864 + (wid * 16 + l15) * 576;
    int cil = kg * 8;
    f32x4 acc[4];
    #pragma unroll
    for (int f = 0; f < 4; ++f) acc[f] = (f32x4)0.0f;

    for (int s = 0; s < 18; ++s) {
        int tap = s >> 1;
        int dh = tap / 3 - 1, dw = tap % 3 - 1;
        int co = ((s & 1) << 5) + cil;           // ci offset within the tap
        short8 araw = *(const short8*)(WbA + tap * 64 + co);
        bf16x8 af = __builtin_bit_cast(bf16x8, araw);
        int doff = (dh * 128 + dw) * 64 + co;
        #pragma unroll
        for (int f = 0; f < 4; ++f) {
            int h2 = hh[f] + dh, w2 = wwv[f] + dw;
            short8 braw = ((unsigned)h2 < 128u && (unsigned)w2 < 128u)
                          ? *(const short8*)(Xb + xb[f] + doff) : (short8)0;
            bf16x8 bfr = __builtin_bit_cast(bf16x8, braw);
            acc[f] = __builtin_amdgcn_mfma_f32_16x16x32_bf16(af, bfr, acc[f], 0, 0, 0);
        }
    }
    float bias[4];
    #pragma unroll
    for (int r = 0; r < 4; ++r) bias[r] = kb[n * 64 + wid * 16 + kg * 4 + r];
    #pragma unroll
    for (int f = 0; f < 4; ++f) {
        if (!val[f]) continue;
        #pragma unroll
        for (int r = 0; r < 4; ++r) {
            int c = wid * 16 + kg * 4 + r;
            float v = acc[f][r] + bias[r];
            out[ob[f] + c * HW] = fmaxf(v, 0.0f);
        }
    }
}

// ---------------------------------------------------------------- K3:
// per-(b,c) instance norm in place on out
__global__ void k_inorm(float* __restrict__ out, const float* __restrict__ gamma,
                        const float* __restrict__ beta) {
    int bc = blockIdx.x;            // b*64 + c
    int c  = bc & 63;
    float* ptr = out + (size_t)bc * HW;
    int t = threadIdx.x;
    float s = 0.f, s2 = 0.f;
    const float4* p4 = (const float4*)ptr;
    #pragma unroll
    for (int i = 0; i < 16; ++i) {
        float4 v = p4[t + i * 256];
        s  += v.x + v.y + v.z + v.w;
        s2 += v.x*v.x + v.y*v.y + v.z*v.z + v.w*v.w;
    }
    #pragma unroll
    for (int off = 32; off > 0; off >>= 1) {
        s  += __shfl_down(s, off);
        s2 += __shfl_down(s2, off);
    }
    __shared__ float rs[4], rs2[4], stat[2];
    int wid = t >> 6, lane = t & 63;
    if (lane == 0) { rs[wid] = s; rs2[wid] = s2; }
    __syncthreads();
    if (t == 0) {
        float S  = rs[0] + rs[1] + rs[2] + rs[3];
        float S2 = rs2[0] + rs2[1] + rs2[2] + rs2[3];
        float mu  = S * (1.0f / HW);
        float var = S2 * (1.0f / HW) - mu * mu;
        stat[0] = mu;
        stat[1] = rsqrtf(var + 1e-5f);
    }
    __syncthreads();
    float mu = stat[0], rstd = stat[1];
    float g = gamma[c], bt = beta[c];
    float4* o4 = (float4*)ptr;
    #pragma unroll
    for (int i = 0; i < 16; ++i) {
        float4 v = o4[t + i * 256];
        v.x = (v.x - mu) * rstd * g + bt;
        v.y = (v.y - mu) * rstd * g + bt;
        v.z = (v.z - mu) * rstd * g + bt;
        v.w = (v.w - mu) * rstd * g + bt;
        o4[t + i * 256] = v;
    }
}

extern "C" void kernel_launch(void* const* d_in, const int* in_sizes, int n_in,
                              void* d_out, int out_size, void* d_ws, size_t ws_size,
                              hipStream_t stream) {
    const float* x    = (const float*)d_in[0];
    const float* kw   = (const float*)d_in[1];
    const float* kb   = (const float*)d_in[2];
    const float* w1   = (const float*)d_in[3];
    const float* b1   = (const float*)d_in[4];
    const float* w2   = (const float*)d_in[5];
    const float* b2   = (const float*)d_in[6];
    const float* gam  = (const float*)d_in[7];
    const float* bet  = (const float*)d_in[8];
    float* out = (float*)d_out;

    char* ws = (char*)d_ws;
    unsigned* gcnt        = (unsigned*)ws;                    // 9 u32 (64 B pad)
    unsigned* lists       = (unsigned*)(ws + 64);             // 9*131072 u32
    unsigned short* Xb    = (unsigned short*)(ws + 4718656);  // 8*128*128*64 bf16
    unsigned short* Wb    = (unsigned short*)(ws + 21495872); // 9*64*9*64 bf16
    // total ws usage: ~22.2 MB

    hipMemsetAsync(gcnt, 0, 64, stream);
    k_x_to_bf16_nhwc<<<dim3(2, 128, 8), 256, 0, stream>>>(x, Xb);
    k_w_to_bf16<<<1296, 256, 0, stream>>>(kw, Wb);
    k_scores_bin<<<512, 256, 0, stream>>>(x, w1, b1, w2, b2, gcnt, lists);
    k_conv_sel<<<dim3(2048, NPATH), 256, 0, stream>>>(Xb, Wb, kb, gcnt, lists, out);
    k_inorm<<<512, 256, 0, stream>>>(out, gam, bet);
}